// Round 1
// baseline (181.212 us; speedup 1.0000x reference)
//
#include <hip/hip_runtime.h>

// QRNN: SEQ=4096, BATCH=8, CIN=256, HID=256, K=2 (lookback=1)
// Pipeline:
//   1) pack_x: X fp32 -> bf16 with one zero row in front (Xp[t]=X[t-1], Xp[0]=0)
//   2) pack_w: Wz,Wf (H,C,2) fp32 -> Bmat bf16 [n][kin] (n<256:Z, else F; kin<256: tap0 (X[s-1]), else tap1 (X[s]))
//   3) gemm:  out[m,n] = sum_kin A[m,kin]*Bmat[n,kin], A[m,k<256]=Xp[m*256+k], A[m,k>=256]=Xp[m*256+1792+k]
//             epilogue: z'=quickgelu(z+bz) -> d_out (scratch, same layout as H), f'=sigmoid(f+bf) -> ws_f
//   4) scanA: per (channel, 64-chunk): A=prod(1-f), C=chunk scan from 0
//   5) scanB: per channel: scan over 64 chunks -> h at chunk starts + h_last
//   6) scanC: per (channel, chunk): replay recurrence, overwrite d_out with h
//
// ws layout (bytes):  ws_f fp32 33,554,432 | Xbf 16,781,312 | Bmat 524,288 |
//                     Ac 524,288 | Cc 524,288 | Hs 524,288   (total ~52.4 MB)

#define SEQn 4096
#define BATCHn 8
#define NCH 2048          // BATCH*HID channels
#define CHUNK 64
#define NCHUNK 64

typedef __attribute__((ext_vector_type(8))) short bf16x8;
typedef __attribute__((ext_vector_type(4))) float floatx4;

__device__ __forceinline__ unsigned short f2bf(float x) {
  unsigned int u = __float_as_uint(x);
  u += 0x7fffu + ((u >> 16) & 1u);     // round-to-nearest-even
  return (unsigned short)(u >> 16);
}

__device__ __forceinline__ float sigf(float x) {
  return 1.0f / (1.0f + __expf(-x));
}

// ---- 1) pack X: bf16 with zero pad row in front ----
__global__ void pack_x_kernel(const float* __restrict__ X, ushort* __restrict__ Xbf) {
  int idx = blockIdx.x * blockDim.x + threadIdx.x;
  const int total4 = ((SEQn + 1) * NCH) / 4;     // 2,097,664
  if (idx >= total4) return;
  const int pad4 = NCH / 4;                      // 512 (one padded seq row)
  float4 v;
  if (idx < pad4) { v.x = 0.f; v.y = 0.f; v.z = 0.f; v.w = 0.f; }
  else v = ((const float4*)X)[idx - pad4];
  ushort4 o;
  o.x = f2bf(v.x); o.y = f2bf(v.y); o.z = f2bf(v.z); o.w = f2bf(v.w);
  ((ushort4*)Xbf)[idx] = o;
}

// ---- 2) pack W into Bmat[n*512+kin] bf16 ----
__global__ void pack_w_kernel(const float* __restrict__ Wz, const float* __restrict__ Wf,
                              ushort* __restrict__ Bm) {
  int idx = blockIdx.x * blockDim.x + threadIdx.x;   // 0..262143
  if (idx >= 512 * 512) return;
  int n = idx >> 9, kin = idx & 511;
  const float* W = (n < 256) ? Wz : Wf;
  int h = n & 255;
  int c = kin & 255;
  int tap = kin >> 8;                 // kin<256 -> k=0 (pairs with X[s-1]), else k=1
  Bm[idx] = f2bf(W[h * 512 + c * 2 + tap]);
}

// ---- 3) GEMM 128x128 tile, mfma_f32_16x16x32_bf16, fused activations ----
__global__ __launch_bounds__(256) void gemm_kernel(
    const ushort* __restrict__ Xbf, const ushort* __restrict__ Bm,
    const float* __restrict__ bz, const float* __restrict__ bfb,
    float* __restrict__ zout, float* __restrict__ fout) {
  __shared__ __align__(16) ushort sA[128 * 32];
  __shared__ __align__(16) ushort sB[128 * 32];
  const int tid  = threadIdx.x;
  const int wave = tid >> 6;
  const int lane = tid & 63;
  const int quad = lane >> 4;
  const int lrow = lane & 15;
  const int wm = wave >> 1;          // 2x2 wave grid, each wave 64x64
  const int wn = wave & 1;
  const int bm = blockIdx.x;         // 0..255 (M tiles)
  const int bn = blockIdx.y;         // 0..3   (N tiles)

  floatx4 acc[4][4];
#pragma unroll
  for (int i = 0; i < 4; ++i)
#pragma unroll
    for (int j = 0; j < 4; ++j)
      acc[i][j] = (floatx4){0.f, 0.f, 0.f, 0.f};

  // staging: 512 16B segments per tile, 2 per thread; seg g -> row g>>2, kseg g&3
  const int g0 = tid, g1 = tid + 256;
  const int m0 = g0 >> 2, ks0 = (g0 & 3) * 8;
  const int m1 = g1 >> 2, ks1 = (g1 & 3) * 8;

  for (int k0 = 0; k0 < 512; k0 += 32) {
    const int kk0 = k0 + ks0, kk1 = k0 + ks1;
    const int cA0 = (kk0 < 256) ? kk0 : kk0 + 1792;   // second conv tap lives +2048-256
    const int cA1 = (kk1 < 256) ? kk1 : kk1 + 1792;
    uint4 av0 = *(const uint4*)(Xbf + ((size_t)(bm * 128 + m0) * 256 + cA0));
    uint4 av1 = *(const uint4*)(Xbf + ((size_t)(bm * 128 + m1) * 256 + cA1));
    uint4 bv0 = *(const uint4*)(Bm  + ((size_t)(bn * 128 + m0) * 512 + kk0));
    uint4 bv1 = *(const uint4*)(Bm  + ((size_t)(bn * 128 + m1) * 512 + kk1));
    __syncthreads();                 // previous iter's ds_reads done
    ((uint4*)sA)[g0] = av0;
    ((uint4*)sA)[g1] = av1;
    ((uint4*)sB)[g0] = bv0;
    ((uint4*)sB)[g1] = bv1;
    __syncthreads();

    bf16x8 af[4], bfr[4];
#pragma unroll
    for (int fi = 0; fi < 4; ++fi)
      af[fi] = *(const bf16x8*)&sA[(wm * 64 + fi * 16 + lrow) * 32 + quad * 8];
#pragma unroll
    for (int fj = 0; fj < 4; ++fj)
      bfr[fj] = *(const bf16x8*)&sB[(wn * 64 + fj * 16 + lrow) * 32 + quad * 8];
#pragma unroll
    for (int fi = 0; fi < 4; ++fi)
#pragma unroll
      for (int fj = 0; fj < 4; ++fj)
        acc[fi][fj] = __builtin_amdgcn_mfma_f32_16x16x32_bf16(af[fi], bfr[fj], acc[fi][fj], 0, 0, 0);
  }

  // epilogue: C/D layout col=lane&15, row=quad*4+reg (m89/m91)
  const bool isZ = (bn < 2);
#pragma unroll
  for (int fi = 0; fi < 4; ++fi) {
    const int mg = bm * 128 + wm * 64 + fi * 16 + quad * 4;
#pragma unroll
    for (int fj = 0; fj < 4; ++fj) {
      const int ng = bn * 128 + wn * 64 + fj * 16 + lrow;
#pragma unroll
      for (int r = 0; r < 4; ++r) {
        float v = acc[fi][fj][r];
        const int m = mg + r;
        if (isZ) {
          v += bz[ng];
          zout[(size_t)m * 256 + ng] = v * sigf(1.702f * v);   // QuickGELU
        } else {
          const int h = ng - 256;
          v += bfb[h];
          fout[(size_t)m * 256 + h] = sigf(v);
        }
      }
    }
  }
}

// ---- 4) per-chunk reduction: A=prod(1-f), C = scan offset ----
__global__ void scanA_kernel(const float* __restrict__ z, const float* __restrict__ f,
                             float* __restrict__ Ac, float* __restrict__ Cc) {
  int t = blockIdx.x * blockDim.x + threadIdx.x;   // 0..131071
  int ch = t & (NCH - 1);
  int j = t >> 11;
  const float* zp = z + (size_t)j * CHUNK * NCH + ch;
  const float* fp = f + (size_t)j * CHUNK * NCH + ch;
  float A = 1.0f, C = 0.0f;
#pragma unroll 8
  for (int i = 0; i < CHUNK; ++i) {
    float fv = fp[(size_t)i * NCH];
    float zv = zp[(size_t)i * NCH];
    float a = 1.0f - fv;
    C = fmaf(a, C, fv * zv);
    A *= a;
  }
  Ac[t] = A;
  Cc[t] = C;
}

// ---- 5) cross-chunk scan (2048 channels) ----
__global__ void scanB_kernel(const float* __restrict__ hidden,
                             const float* __restrict__ Ac, const float* __restrict__ Cc,
                             float* __restrict__ Hs, float* __restrict__ out) {
  int ch = blockIdx.x * blockDim.x + threadIdx.x;   // 0..2047
  float h = hidden[ch];
#pragma unroll 8
  for (int j = 0; j < NCHUNK; ++j) {
    Hs[j * NCH + ch] = h;
    h = fmaf(Ac[j * NCH + ch], h, Cc[j * NCH + ch]);
  }
  out[(size_t)SEQn * NCH + ch] = h;                 // h_last
}

// ---- 6) replay within chunk, overwrite z' with h ----
__global__ void scanC_kernel(float* __restrict__ zh, const float* __restrict__ f,
                             const float* __restrict__ Hs) {
  int t = blockIdx.x * blockDim.x + threadIdx.x;
  int ch = t & (NCH - 1);
  int j = t >> 11;
  float h = Hs[t];
  float* zp = zh + (size_t)j * CHUNK * NCH + ch;
  const float* fp = f + (size_t)j * CHUNK * NCH + ch;
#pragma unroll 4
  for (int i = 0; i < CHUNK; ++i) {
    float fv = fp[(size_t)i * NCH];
    float zv = zp[(size_t)i * NCH];
    h = fmaf(fv, zv - h, h);        // f*z + (1-f)*h
    zp[(size_t)i * NCH] = h;
  }
  if (j == NCHUNK - 1) zh[(size_t)SEQn * NCH + ch] = h;  // keep h_last == H[4095]
}

extern "C" void kernel_launch(void* const* d_in, const int* in_sizes, int n_in,
                              void* d_out, int out_size, void* d_ws, size_t ws_size,
                              hipStream_t stream) {
  const float* X      = (const float*)d_in[0];
  const float* hidden = (const float*)d_in[1];
  const float* Wz     = (const float*)d_in[2];
  const float* bz     = (const float*)d_in[3];
  const float* Wf     = (const float*)d_in[4];
  const float* bfb    = (const float*)d_in[5];
  float* out = (float*)d_out;

  char* ws = (char*)d_ws;
  float*  ws_f = (float*)ws;                          // f' fp32, 33,554,432 B
  ushort* Xbf  = (ushort*)(ws + 33554432);            // padded X bf16
  ushort* Bm   = (ushort*)(ws + 50335744);            // packed weights bf16
  float*  Ac   = (float*)(ws + 50860032);
  float*  Cc   = (float*)(ws + 51384320);
  float*  Hs   = (float*)(ws + 51908608);

  pack_x_kernel<<<8194, 256, 0, stream>>>(X, Xbf);
  pack_w_kernel<<<1024, 256, 0, stream>>>(Wz, Wf, Bm);
  dim3 ggrid(256, 4);
  gemm_kernel<<<ggrid, 256, 0, stream>>>(Xbf, Bm, bz, bfb, out, ws_f);
  scanA_kernel<<<512, 256, 0, stream>>>(out, ws_f, Ac, Cc);
  scanB_kernel<<<8, 256, 0, stream>>>(hidden, Ac, Cc, Hs, out);
  scanC_kernel<<<512, 256, 0, stream>>>(out, ws_f, Hs);
}

// Round 2
// 160.062 us; speedup vs baseline: 1.1321x; 1.1321x over previous
//
#include <hip/hip_runtime.h>

// QRNN: SEQ=4096, BATCH=8, CIN=256, HID=256, K=2 (lookback=1)
// R2: global_load_lds staging, bf16 z'/f', LDS-transposed epilogue,
//     CHUNK=32/NCHUNK=128 scans, wave-shfl cross-chunk scan.
//
// ws layout (bytes): zbf 16,777,216 | fbf 16,777,216 | Xbf 16,781,312 | Bm 524,288
//                    Ac/Cc/Hs (3 MB) aliased over Xbf (dead after gemm). Total 50.86 MB.

#define SEQn 4096
#define NCH 2048          // BATCH*HID channels
#define CHUNK 32
#define NCHUNK 128

typedef __attribute__((ext_vector_type(8))) short bf16x8;
typedef __attribute__((ext_vector_type(4))) float floatx4;

__device__ __forceinline__ unsigned short f2bf(float x) {
  unsigned int u = __float_as_uint(x);
  u += 0x7fffu + ((u >> 16) & 1u);     // RNE
  return (unsigned short)(u >> 16);
}
__device__ __forceinline__ float bf2f(ushort u) {
  return __uint_as_float((unsigned int)u << 16);
}
__device__ __forceinline__ float sigf(float x) {
  return 1.0f / (1.0f + __expf(-x));
}

// ---- 1) pack X: bf16 with one zero seq-row (2048 elems) in front ----
__global__ void pack_x_kernel(const float* __restrict__ X, ushort* __restrict__ Xbf) {
  int idx = blockIdx.x * blockDim.x + threadIdx.x;
  const int total4 = ((SEQn + 1) * NCH) / 4;     // 2,097,664
  if (idx >= total4) return;
  const int pad4 = NCH / 4;
  float4 v;
  if (idx < pad4) { v.x = 0.f; v.y = 0.f; v.z = 0.f; v.w = 0.f; }
  else v = ((const float4*)X)[idx - pad4];
  ushort4 o;
  o.x = f2bf(v.x); o.y = f2bf(v.y); o.z = f2bf(v.z); o.w = f2bf(v.w);
  ((ushort4*)Xbf)[idx] = o;
}

// ---- 2) pack W into Bmat[n*512+kin] bf16 (n<256:Z else F; kin<256: tap0) ----
__global__ void pack_w_kernel(const float* __restrict__ Wz, const float* __restrict__ Wf,
                              ushort* __restrict__ Bm) {
  int idx = blockIdx.x * blockDim.x + threadIdx.x;
  if (idx >= 512 * 512) return;
  int n = idx >> 9, kin = idx & 511;
  const float* W = (n < 256) ? Wz : Wf;
  int h = n & 255, c = kin & 255, tap = kin >> 8;
  Bm[idx] = f2bf(W[h * 512 + c * 2 + tap]);
}

// ---- 3) GEMM 128x128, mfma_f32_16x16x32_bf16, global_load_lds staging ----
__global__ __launch_bounds__(256) void gemm_kernel(
    const ushort* __restrict__ Xbf, const ushort* __restrict__ Bm,
    const float* __restrict__ bz, const float* __restrict__ bfb,
    ushort* __restrict__ zout, ushort* __restrict__ fout) {
  __shared__ __align__(16) ushort smem[8192];   // sA 4096 | sB 4096; reused as 64x128 sT
  ushort* sA = smem;
  ushort* sB = smem + 4096;
  const int tid  = threadIdx.x;
  const int wave = tid >> 6;
  const int lane = tid & 63;
  const int quad = lane >> 4;
  const int lrow = lane & 15;
  const int wm = wave >> 1;          // 2x2 wave grid, 64x64 each
  const int wn = wave & 1;
  const int bm = blockIdx.x;         // 0..255
  const int bn = blockIdx.y;         // 0..3 (0,1=Z cols; 2,3=F cols)

  floatx4 acc[4][4];
#pragma unroll
  for (int i = 0; i < 4; ++i)
#pragma unroll
    for (int j = 0; j < 4; ++j)
      acc[i][j] = (floatx4){0.f, 0.f, 0.f, 0.f};

  // staging: seg g -> row g>>2, k-seg (g&3)*8. g0=tid (rows 0..63), g1=tid+256 (rows 64..127)
  const int mr0 = tid >> 2;               // 0..63
  const int ks  = (tid & 3) * 8;
  const size_t aRow0 = (size_t)(bm * 128 + mr0) * 256;
  const size_t aRow1 = (size_t)(bm * 128 + 64 + mr0) * 256;
  const size_t bRow0 = (size_t)(bn * 128 + mr0) * 512;
  const size_t bRow1 = (size_t)(bn * 128 + 64 + mr0) * 512;
  char* ldsA0 = (char*)sA + wave * 1024;
  char* ldsA1 = (char*)sA + 4096 + wave * 1024;
  char* ldsB0 = (char*)sB + wave * 1024;
  char* ldsB1 = (char*)sB + 4096 + wave * 1024;

  for (int k0 = 0; k0 < 512; k0 += 32) {
    const int kk = k0 + ks;
    const int cA = (kk < 256) ? kk : kk + 1792;   // tap1 lives +2048-256
    __syncthreads();                               // prev iter ds_reads done
    __builtin_amdgcn_global_load_lds(
        (const __attribute__((address_space(1))) void*)(Xbf + aRow0 + cA),
        (__attribute__((address_space(3))) void*)ldsA0, 16, 0, 0);
    __builtin_amdgcn_global_load_lds(
        (const __attribute__((address_space(1))) void*)(Xbf + aRow1 + cA),
        (__attribute__((address_space(3))) void*)ldsA1, 16, 0, 0);
    __builtin_amdgcn_global_load_lds(
        (const __attribute__((address_space(1))) void*)(Bm + bRow0 + kk),
        (__attribute__((address_space(3))) void*)ldsB0, 16, 0, 0);
    __builtin_amdgcn_global_load_lds(
        (const __attribute__((address_space(1))) void*)(Bm + bRow1 + kk),
        (__attribute__((address_space(3))) void*)ldsB1, 16, 0, 0);
    __syncthreads();                               // vmcnt drained by compiler

    bf16x8 af[4], bfr[4];
#pragma unroll
    for (int fi = 0; fi < 4; ++fi)
      af[fi] = *(const bf16x8*)&sA[(wm * 64 + fi * 16 + lrow) * 32 + quad * 8];
#pragma unroll
    for (int fj = 0; fj < 4; ++fj)
      bfr[fj] = *(const bf16x8*)&sB[(wn * 64 + fj * 16 + lrow) * 32 + quad * 8];
#pragma unroll
    for (int fi = 0; fi < 4; ++fi)
#pragma unroll
      for (int fj = 0; fj < 4; ++fj)
        acc[fi][fj] = __builtin_amdgcn_mfma_f32_16x16x32_bf16(af[fi], bfr[fj], acc[fi][fj], 0, 0, 0);
  }

  // epilogue: activation -> bf16 -> sT (64x128) in 2 rounds -> coalesced dwordx4 stores
  const bool isZ = (bn < 2);
  ushort* gout = isZ ? zout : fout;
  const int ncol0 = (bn & 1) * 128;
  const float* bias = isZ ? bz : bfb;
  float bv[4];
#pragma unroll
  for (int fj = 0; fj < 4; ++fj)
    bv[fj] = bias[ncol0 + wn * 64 + fj * 16 + lrow];

  for (int round = 0; round < 2; ++round) {
    __syncthreads();
    if (wm == round) {
#pragma unroll
      for (int fi = 0; fi < 4; ++fi)
#pragma unroll
        for (int fj = 0; fj < 4; ++fj)
#pragma unroll
          for (int r = 0; r < 4; ++r) {
            float v = acc[fi][fj][r] + bv[fj];
            float o = isZ ? (v * sigf(1.702f * v)) : sigf(v);
            smem[(fi * 16 + quad * 4 + r) * 128 + wn * 64 + fj * 16 + lrow] = f2bf(o);
          }
    }
    __syncthreads();
#pragma unroll
    for (int it = 0; it < 4; ++it) {
      int e = tid + it * 256;           // 1024 segs = 64 rows x 16 segs
      int row = e >> 4, seg = e & 15;
      uint4 v = *(uint4*)&smem[row * 128 + seg * 8];
      *(uint4*)(gout + (size_t)(bm * 128 + round * 64 + row) * 256 + ncol0 + seg * 8) = v;
    }
  }
}

// ---- 4) per-chunk (32-step) reduction: A=prod(1-f), C=chunk scan from 0 ----
__global__ void scanA_kernel(const ushort* __restrict__ z, const ushort* __restrict__ f,
                             float* __restrict__ Ac, float* __restrict__ Cc) {
  int t = blockIdx.x * blockDim.x + threadIdx.x;   // 0..262143
  int ch = t & (NCH - 1);
  int j = t >> 11;                                  // 0..127
  const ushort* zp = z + (size_t)j * CHUNK * NCH + ch;
  const ushort* fp = f + (size_t)j * CHUNK * NCH + ch;
  float A = 1.0f, C = 0.0f;
#pragma unroll
  for (int i = 0; i < CHUNK; ++i) {
    float fv = bf2f(fp[(size_t)i * NCH]);
    float zv = bf2f(zp[(size_t)i * NCH]);
    float a = 1.0f - fv;
    C = fmaf(a, C, fv * zv);
    A *= a;
  }
  Ac[t] = A;
  Cc[t] = C;
}

// ---- 5) cross-chunk scan: one wave per channel, shfl Hillis-Steele ----
__global__ void scanB_kernel(const float* __restrict__ hidden,
                             const float* __restrict__ Ac, const float* __restrict__ Cc,
                             float* __restrict__ Hs) {
  const int lane = threadIdx.x & 63;
  const int ch = blockIdx.x * 4 + (threadIdx.x >> 6);   // 512 blocks x 4 waves
  const int j0 = 2 * lane, j1 = 2 * lane + 1;
  float a0 = Ac[j0 * NCH + ch], c0 = Cc[j0 * NCH + ch];
  float a1 = Ac[j1 * NCH + ch], c1 = Cc[j1 * NCH + ch];
  // per-lane element: chunk j0 then j1
  float a = a0 * a1;
  float c = fmaf(a1, c0, c1);
  // inclusive scan, compose(prev-from-lower-lane, cur): T = cur ∘ prev
#pragma unroll
  for (int d = 1; d < 64; d <<= 1) {
    float pa = __shfl_up(a, d, 64);
    float pc = __shfl_up(c, d, 64);
    if (lane >= d) { c = fmaf(a, pc, c); a *= pa; }
  }
  // exclusive prefix
  float xa = __shfl_up(a, 1, 64), xc = __shfl_up(c, 1, 64);
  if (lane == 0) { xa = 1.0f; xc = 0.0f; }
  float h0 = hidden[ch];
  float hs0 = fmaf(xa, h0, xc);          // h at start of chunk j0
  Hs[j0 * NCH + ch] = hs0;
  Hs[j1 * NCH + ch] = fmaf(a0, hs0, c0); // h at start of chunk j1
}

// ---- 6) replay within chunk, write fp32 H (+ h_last) ----
__global__ void scanC_kernel(const ushort* __restrict__ z, const ushort* __restrict__ f,
                             const float* __restrict__ Hs, float* __restrict__ out) {
  int t = blockIdx.x * blockDim.x + threadIdx.x;
  int ch = t & (NCH - 1);
  int j = t >> 11;
  float h = Hs[t];
  const ushort* zp = z + (size_t)j * CHUNK * NCH + ch;
  const ushort* fp = f + (size_t)j * CHUNK * NCH + ch;
  float* op = out + (size_t)j * CHUNK * NCH + ch;
#pragma unroll
  for (int i = 0; i < CHUNK; ++i) {
    float fv = bf2f(fp[(size_t)i * NCH]);
    float zv = bf2f(zp[(size_t)i * NCH]);
    h = fmaf(fv, zv - h, h);             // f*z + (1-f)*h
    op[(size_t)i * NCH] = h;
  }
  if (j == NCHUNK - 1) out[(size_t)SEQn * NCH + ch] = h;  // h_last row
}

extern "C" void kernel_launch(void* const* d_in, const int* in_sizes, int n_in,
                              void* d_out, int out_size, void* d_ws, size_t ws_size,
                              hipStream_t stream) {
  const float* X      = (const float*)d_in[0];
  const float* hidden = (const float*)d_in[1];
  const float* Wz     = (const float*)d_in[2];
  const float* bz     = (const float*)d_in[3];
  const float* Wf     = (const float*)d_in[4];
  const float* bfb    = (const float*)d_in[5];
  float* out = (float*)d_out;

  char* ws = (char*)d_ws;
  ushort* zbf = (ushort*)ws;                       // 16,777,216 B
  ushort* fbf = (ushort*)(ws + 16777216);          // 16,777,216 B
  ushort* Xbf = (ushort*)(ws + 33554432);          // 16,781,312 B (dead after gemm)
  ushort* Bm  = (ushort*)(ws + 50335744);          //    524,288 B
  // aliased over Xbf region (only used after gemm completes):
  float* Ac = (float*)(ws + 33554432);             // 1 MB
  float* Cc = (float*)(ws + 34603008);             // 1 MB
  float* Hs = (float*)(ws + 35651584);             // 1 MB

  pack_x_kernel<<<8194, 256, 0, stream>>>(X, Xbf);
  pack_w_kernel<<<1024, 256, 0, stream>>>(Wz, Wf, Bm);
  dim3 ggrid(256, 4);
  gemm_kernel<<<ggrid, 256, 0, stream>>>(Xbf, Bm, bz, bfb, zbf, fbf);
  scanA_kernel<<<1024, 256, 0, stream>>>(zbf, fbf, Ac, Cc);
  scanB_kernel<<<512, 256, 0, stream>>>(hidden, Ac, Cc, Hs);
  scanC_kernel<<<1024, 256, 0, stream>>>(zbf, fbf, Hs, out);
}

// Round 3
// 145.141 us; speedup vs baseline: 1.2485x; 1.1028x over previous
//
#include <hip/hip_runtime.h>

// QRNN: SEQ=4096, BATCH=8, CIN=256, HID=256, K=2 (lookback=1)
// R3: BK=64 GEMM (32 MFMA/barrier), XOR-swizzled LDS (conflict-free frag reads),
//     padded epilogue transpose, fast sigmoid, merged pack, vectorized scans.
//
// ws: zbf 16MB | fbf 16MB | Xbf 16MB (dead after gemm; Ac/Cc/Hs aliased) | Bm 0.5MB

#define SEQn 4096
#define NCH 2048          // BATCH*HID channels
#define CHUNK 32
#define NCHUNK 128

typedef __attribute__((ext_vector_type(8))) short bf16x8;
typedef __attribute__((ext_vector_type(4))) float floatx4;

__device__ __forceinline__ unsigned short f2bf(float x) {
  unsigned int u = __float_as_uint(x);
  u += 0x7fffu + ((u >> 16) & 1u);     // RNE
  return (unsigned short)(u >> 16);
}
__device__ __forceinline__ float bf2f(ushort u) {
  return __uint_as_float((unsigned int)u << 16);
}
__device__ __forceinline__ float sigf(float x) {
  return __builtin_amdgcn_rcpf(1.0f + __expf(-x));
}

// ---- 1) merged pack: blocks [0,1024) pack W, blocks [1024,9218) pack X ----
__global__ void pack_kernel(const float* __restrict__ X,
                            const float* __restrict__ Wz, const float* __restrict__ Wf,
                            ushort* __restrict__ Xbf, ushort* __restrict__ Bm) {
  if (blockIdx.x < 1024) {
    int idx = blockIdx.x * 256 + threadIdx.x;        // 0..262143
    int n = idx >> 9, kin = idx & 511;
    const float* W = (n < 256) ? Wz : Wf;
    int h = n & 255, c = kin & 255, tap = kin >> 8;  // kin<256: tap0 (X[s-1])
    Bm[idx] = f2bf(W[h * 512 + c * 2 + tap]);
  } else {
    int idx = (blockIdx.x - 1024) * 256 + threadIdx.x;
    const int total4 = ((SEQn + 1) * NCH) / 4;       // 2,097,664
    if (idx >= total4) return;
    const int pad4 = NCH / 4;
    float4 v;
    if (idx < pad4) { v.x = 0.f; v.y = 0.f; v.z = 0.f; v.w = 0.f; }
    else v = ((const float4*)X)[idx - pad4];
    ushort4 o;
    o.x = f2bf(v.x); o.y = f2bf(v.y); o.z = f2bf(v.z); o.w = f2bf(v.w);
    ((ushort4*)Xbf)[idx] = o;
  }
}

// ---- 2) GEMM 128x128, BK=64, mfma_f32_16x16x32_bf16, swizzled LDS ----
// LDS seg (row, s) holds global k-seg s^(row&7)  (seg = 16B = 8 bf16)
__global__ __launch_bounds__(256) void gemm_kernel(
    const ushort* __restrict__ Xbf, const ushort* __restrict__ Bm,
    const float* __restrict__ bz, const float* __restrict__ bfb,
    ushort* __restrict__ zout, ushort* __restrict__ fout) {
  __shared__ __align__(16) char smem_raw[32768];
  ushort* sA = (ushort*)smem_raw;                 // 128 rows x 64 k
  ushort* sB = (ushort*)(smem_raw + 16384);       // 128 cols x 64 k
  ushort* sT = (ushort*)smem_raw;                 // epilogue 64 x 136

  const int tid  = threadIdx.x;
  const int wave = tid >> 6;
  const int lane = tid & 63;
  const int quad = lane >> 4;
  const int lrow = lane & 15;
  const int wm = wave >> 1;          // 2x2 wave grid, 64x64 each
  const int wn = wave & 1;
  const int bm = blockIdx.x;         // 0..255
  const int bn = blockIdx.y;         // 0..3 (0,1=Z; 2,3=F)

  floatx4 acc[4][4];
#pragma unroll
  for (int i = 0; i < 4; ++i)
#pragma unroll
    for (int j = 0; j < 4; ++j)
      acc[i][j] = (floatx4){0.f, 0.f, 0.f, 0.f};

  // staging coords: 4 segs each for A and B per thread
  int rowS[4], gko[4];               // LDS row, global k-seg offset (elements)
#pragma unroll
  for (int it = 0; it < 4; ++it) {
    int g = wave * 256 + it * 64 + lane;     // LDS seg index 0..1023
    int row = g >> 3, ks8 = g & 7;
    rowS[it] = row;
    gko[it] = (ks8 ^ (row & 7)) * 8;         // swizzled global k offset
  }
  char* ldsA = (char*)sA + wave * 4096 + (lane << 4);
  char* ldsB = (char*)sB + wave * 4096 + (lane << 4);

  for (int k0 = 0; k0 < 512; k0 += 64) {
    __syncthreads();                 // prev iter ds_reads done
#pragma unroll
    for (int it = 0; it < 4; ++it) {
      const int kk = k0 + gko[it];
      const int cA = (kk < 256) ? kk : kk + 1792;     // tap1 lives +2048-256
      __builtin_amdgcn_global_load_lds(
          (const __attribute__((address_space(1))) void*)(Xbf + (size_t)(bm * 128 + rowS[it]) * 256 + cA),
          (__attribute__((address_space(3))) void*)(ldsA + it * 1024), 16, 0, 0);
      __builtin_amdgcn_global_load_lds(
          (const __attribute__((address_space(1))) void*)(Bm + (size_t)(bn * 128 + rowS[it]) * 512 + kk),
          (__attribute__((address_space(3))) void*)(ldsB + it * 1024), 16, 0, 0);
    }
    __syncthreads();

    bf16x8 af[4][2], bfr[4][2];
#pragma unroll
    for (int fi = 0; fi < 4; ++fi) {
      const int r = wm * 64 + fi * 16 + lrow;
#pragma unroll
      for (int ks = 0; ks < 2; ++ks) {
        const int s = (ks * 4 + quad) ^ (r & 7);
        af[fi][ks] = *(const bf16x8*)&sA[r * 64 + s * 8];
      }
    }
#pragma unroll
    for (int fj = 0; fj < 4; ++fj) {
      const int r = wn * 64 + fj * 16 + lrow;
#pragma unroll
      for (int ks = 0; ks < 2; ++ks) {
        const int s = (ks * 4 + quad) ^ (r & 7);
        bfr[fj][ks] = *(const bf16x8*)&sB[r * 64 + s * 8];
      }
    }
#pragma unroll
    for (int ks = 0; ks < 2; ++ks)
#pragma unroll
      for (int fi = 0; fi < 4; ++fi)
#pragma unroll
        for (int fj = 0; fj < 4; ++fj)
          acc[fi][fj] = __builtin_amdgcn_mfma_f32_16x16x32_bf16(af[fi][ks], bfr[fj][ks], acc[fi][fj], 0, 0, 0);
  }

  // epilogue: activation -> bf16 -> sT (64 x 136 padded) -> coalesced dwordx4
  const bool isZ = (bn < 2);
  ushort* gout = isZ ? zout : fout;
  const int ncol0 = (bn & 1) * 128;
  const float* bias = isZ ? bz : bfb;
  float bv[4];
#pragma unroll
  for (int fj = 0; fj < 4; ++fj)
    bv[fj] = bias[ncol0 + wn * 64 + fj * 16 + lrow];

  for (int round = 0; round < 2; ++round) {
    __syncthreads();
    if (wm == round) {
#pragma unroll
      for (int fi = 0; fi < 4; ++fi)
#pragma unroll
        for (int fj = 0; fj < 4; ++fj)
#pragma unroll
          for (int r = 0; r < 4; ++r) {
            float v = acc[fi][fj][r] + bv[fj];
            float o = isZ ? (v * sigf(1.702f * v)) : sigf(v);
            sT[(fi * 16 + quad * 4 + r) * 136 + wn * 64 + fj * 16 + lrow] = f2bf(o);
          }
    }
    __syncthreads();
#pragma unroll
    for (int it = 0; it < 4; ++it) {
      int e = tid + it * 256;           // 1024 segs = 64 rows x 16 segs
      int row = e >> 4, seg = e & 15;
      uint4 v = *(uint4*)&sT[row * 136 + seg * 8];
      *(uint4*)(gout + (size_t)(bm * 128 + round * 64 + row) * 256 + ncol0 + seg * 8) = v;
    }
  }
}

// ---- 3) per-chunk reduction, 2 channels/thread ----
__global__ void scanA_kernel(const ushort* __restrict__ z, const ushort* __restrict__ f,
                             float* __restrict__ Ac, float* __restrict__ Cc) {
  int t = blockIdx.x * blockDim.x + threadIdx.x;   // 0..131071
  int ch2 = t & 1023;
  int j = t >> 10;                                  // 0..127
  const size_t base = (size_t)j * CHUNK * NCH + 2 * ch2;
  const ushort* zp = z + base;
  const ushort* fp = f + base;
  float A0 = 1.0f, C0 = 0.0f, A1 = 1.0f, C1 = 0.0f;
#pragma unroll
  for (int i = 0; i < CHUNK; ++i) {
    ushort2 fv = *(const ushort2*)(fp + (size_t)i * NCH);
    ushort2 zv = *(const ushort2*)(zp + (size_t)i * NCH);
    float f0 = bf2f(fv.x), f1 = bf2f(fv.y);
    float a0 = 1.0f - f0, a1 = 1.0f - f1;
    C0 = fmaf(a0, C0, f0 * bf2f(zv.x)); A0 *= a0;
    C1 = fmaf(a1, C1, f1 * bf2f(zv.y)); A1 *= a1;
  }
  float2 Av = {A0, A1}, Cv = {C0, C1};
  *(float2*)(Ac + (size_t)j * NCH + 2 * ch2) = Av;
  *(float2*)(Cc + (size_t)j * NCH + 2 * ch2) = Cv;
}

// ---- 4) cross-chunk scan: one wave per channel, shfl Hillis-Steele ----
__global__ void scanB_kernel(const float* __restrict__ hidden,
                             const float* __restrict__ Ac, const float* __restrict__ Cc,
                             float* __restrict__ Hs) {
  const int lane = threadIdx.x & 63;
  const int ch = blockIdx.x * 4 + (threadIdx.x >> 6);   // 512 blocks x 4 waves
  const int j0 = 2 * lane, j1 = 2 * lane + 1;
  float a0 = Ac[j0 * NCH + ch], c0 = Cc[j0 * NCH + ch];
  float a1 = Ac[j1 * NCH + ch], c1 = Cc[j1 * NCH + ch];
  float a = a0 * a1;
  float c = fmaf(a1, c0, c1);
#pragma unroll
  for (int d = 1; d < 64; d <<= 1) {
    float pa = __shfl_up(a, d, 64);
    float pc = __shfl_up(c, d, 64);
    if (lane >= d) { c = fmaf(a, pc, c); a *= pa; }
  }
  float xa = __shfl_up(a, 1, 64), xc = __shfl_up(c, 1, 64);
  if (lane == 0) { xa = 1.0f; xc = 0.0f; }
  float h0 = hidden[ch];
  float hs0 = fmaf(xa, h0, xc);
  Hs[j0 * NCH + ch] = hs0;
  Hs[j1 * NCH + ch] = fmaf(a0, hs0, c0);
}

// ---- 5) replay within chunk, 2 channels/thread, fp32 out ----
__global__ void scanC_kernel(const ushort* __restrict__ z, const ushort* __restrict__ f,
                             const float* __restrict__ Hs, float* __restrict__ out) {
  int t = blockIdx.x * blockDim.x + threadIdx.x;   // 0..131071
  int ch2 = t & 1023;
  int j = t >> 10;
  float2 hv = *(const float2*)(Hs + (size_t)j * NCH + 2 * ch2);
  float h0 = hv.x, h1 = hv.y;
  const size_t base = (size_t)j * CHUNK * NCH + 2 * ch2;
  const ushort* zp = z + base;
  const ushort* fp = f + base;
  float* op = out + base;
#pragma unroll
  for (int i = 0; i < CHUNK; ++i) {
    ushort2 fv = *(const ushort2*)(fp + (size_t)i * NCH);
    ushort2 zv = *(const ushort2*)(zp + (size_t)i * NCH);
    float f0 = bf2f(fv.x), f1 = bf2f(fv.y);
    h0 = fmaf(f0, bf2f(zv.x) - h0, h0);
    h1 = fmaf(f1, bf2f(zv.y) - h1, h1);
    float2 o = {h0, h1};
    *(float2*)(op + (size_t)i * NCH) = o;
  }
  if (j == NCHUNK - 1) {
    float2 o = {h0, h1};
    *(float2*)(out + (size_t)SEQn * NCH + 2 * ch2) = o;   // h_last row
  }
}

extern "C" void kernel_launch(void* const* d_in, const int* in_sizes, int n_in,
                              void* d_out, int out_size, void* d_ws, size_t ws_size,
                              hipStream_t stream) {
  const float* X      = (const float*)d_in[0];
  const float* hidden = (const float*)d_in[1];
  const float* Wz     = (const float*)d_in[2];
  const float* bz     = (const float*)d_in[3];
  const float* Wf     = (const float*)d_in[4];
  const float* bfb    = (const float*)d_in[5];
  float* out = (float*)d_out;

  char* ws = (char*)d_ws;
  ushort* zbf = (ushort*)ws;                       // 16,777,216 B
  ushort* fbf = (ushort*)(ws + 16777216);          // 16,777,216 B
  ushort* Xbf = (ushort*)(ws + 33554432);          // 16,781,312 B (dead after gemm)
  ushort* Bm  = (ushort*)(ws + 50335744);          //    524,288 B
  // aliased over Xbf (used only after gemm completes):
  float* Ac = (float*)(ws + 33554432);
  float* Cc = (float*)(ws + 34603008);
  float* Hs = (float*)(ws + 35651584);

  pack_kernel<<<9218, 256, 0, stream>>>(X, Wz, Wf, Xbf, Bm);
  dim3 ggrid(256, 4);
  gemm_kernel<<<ggrid, 256, 0, stream>>>(Xbf, Bm, bz, bfb, zbf, fbf);
  scanA_kernel<<<512, 256, 0, stream>>>(zbf, fbf, Ac, Cc);
  scanB_kernel<<<512, 256, 0, stream>>>(hidden, Ac, Cc, Hs);
  scanC_kernel<<<512, 256, 0, stream>>>(zbf, fbf, Hs, out);
}